// Round 1
// baseline (239.934 us; speedup 1.0000x reference)
//
#include <hip/hip_runtime.h>
#include <cstdint>

typedef short bf16x8 __attribute__((ext_vector_type(8)));
typedef float f32x4 __attribute__((ext_vector_type(4)));
typedef uint16_t u16x4 __attribute__((ext_vector_type(4)));

#define MFMA_16x16x32(a, b, c) __builtin_amdgcn_mfma_f32_16x16x32_bf16((a), (b), (c), 0, 0, 0)

static constexpr int BATCH = 2;
static constexpr int HEADS = 12;
static constexpr int NCTX  = 2048;
static constexpr int DH    = 64;
static constexpr int EMB   = 768;

// ---------- bf16 helpers (raw-bit, RN rounding) ----------
__device__ __forceinline__ uint16_t f2bf(float x) {
    uint32_t u = __float_as_uint(x);
    u += 0x7FFFu + ((u >> 16) & 1u);
    return (uint16_t)(u >> 16);
}
__device__ __forceinline__ float bf2f(uint16_t h) {
    return __uint_as_float(((uint32_t)h) << 16);
}

// ---------- convert kernels ----------
__global__ void k_split(const float* __restrict__ src, uint16_t* __restrict__ hi,
                        uint16_t* __restrict__ lo, int n4) {
    int i = blockIdx.x * blockDim.x + threadIdx.x;
    if (i >= n4) return;
    float4 v = reinterpret_cast<const float4*>(src)[i];
    uint16_t h0 = f2bf(v.x), h1 = f2bf(v.y), h2 = f2bf(v.z), h3 = f2bf(v.w);
    u16x4 hv = {h0, h1, h2, h3};
    u16x4 lv = {f2bf(v.x - bf2f(h0)), f2bf(v.y - bf2f(h1)),
                f2bf(v.z - bf2f(h2)), f2bf(v.w - bf2f(h3))};
    reinterpret_cast<u16x4*>(hi)[i] = hv;
    reinterpret_cast<u16x4*>(lo)[i] = lv;
}

__global__ void k_conv(const float* __restrict__ src, uint16_t* __restrict__ dst, int n4) {
    int i = blockIdx.x * blockDim.x + threadIdx.x;
    if (i >= n4) return;
    float4 v = reinterpret_cast<const float4*>(src)[i];
    u16x4 hv = {f2bf(v.x), f2bf(v.y), f2bf(v.z), f2bf(v.w)};
    reinterpret_cast<u16x4*>(dst)[i] = hv;
}

// ---------- flash attention ----------
// grid: (NCTX/64, BATCH*HEADS), block: 256 (4 waves). Wave w owns 16 q-rows.
// Writes out_attn as bf16 hi/lo at layout [b][n][h*64+d] (ready for proj GEMM A-operand).
__global__ __launch_bounds__(256) void k_attn(
        const uint16_t* __restrict__ qh, const uint16_t* __restrict__ ql,
        const uint16_t* __restrict__ kh, const uint16_t* __restrict__ kl,
        const uint16_t* __restrict__ vb,
        uint16_t* __restrict__ xh, uint16_t* __restrict__ xl) {
    const int bh = blockIdx.y;
    const int b  = bh / HEADS;
    const int h  = bh % HEADS;
    const int tid = threadIdx.x;
    const int w = tid >> 6;
    const int l = tid & 63;
    const int g = l >> 4;    // 16-lane group 0..3
    const int c = l & 15;

    // LDS: K tiles padded +8 (row stride 144B, b128 reads 2-way = free);
    // V padded +8 (aligned staging; scalar reads 4-way, accepted round 1);
    // P per-wave, padded to 40 (2-way).
    __shared__ uint16_t Kh_s[32][72];
    __shared__ uint16_t Kl_s[32][72];
    __shared__ uint16_t V_s [32][72];
    __shared__ uint16_t P_s [4][16][40];

    const int q0 = blockIdx.x * 64 + w * 16;

    // Q fragments: A layout m=c, k=8g+j; two k-frags (d 0..31, 32..63), hi+lo
    const size_t qoff = ((size_t)bh * NCTX + q0 + c) * DH + 8 * g;
    bf16x8 qa_h[2], qa_l[2];
    qa_h[0] = *reinterpret_cast<const bf16x8*>(qh + qoff);
    qa_h[1] = *reinterpret_cast<const bf16x8*>(qh + qoff + 32);
    qa_l[0] = *reinterpret_cast<const bf16x8*>(ql + qoff);
    qa_l[1] = *reinterpret_cast<const bf16x8*>(ql + qoff + 32);

    f32x4 zero = {0.f, 0.f, 0.f, 0.f};
    f32x4 o[4] = {zero, zero, zero, zero};
    float mrow[4] = {-1e30f, -1e30f, -1e30f, -1e30f};
    float lrow[4] = {0.f, 0.f, 0.f, 0.f};

    const int srow = tid >> 3;       // 0..31
    const int sch  = tid & 7;        // 0..7 (8 bf16 chunks)

    for (int kv0 = 0; kv0 < NCTX; kv0 += 32) {
        __syncthreads();
        // cooperative stage: 32 rows x 64 cols bf16, one 16B chunk per thread per buffer
        const size_t koff = ((size_t)bh * NCTX + kv0 + srow) * DH + sch * 8;
        *reinterpret_cast<bf16x8*>(&Kh_s[srow][sch * 8]) = *reinterpret_cast<const bf16x8*>(kh + koff);
        *reinterpret_cast<bf16x8*>(&Kl_s[srow][sch * 8]) = *reinterpret_cast<const bf16x8*>(kl + koff);
        *reinterpret_cast<bf16x8*>(&V_s [srow][sch * 8]) = *reinterpret_cast<const bf16x8*>(vb + koff);
        __syncthreads();

        // ---- S = Q K^T (3-term split, fp32 accum). S tile: 16 q-rows x 32 kv.
        f32x4 s[2] = {zero, zero};
#pragma unroll
        for (int nf = 0; nf < 2; ++nf) {
#pragma unroll
            for (int kf = 0; kf < 2; ++kf) {
                bf16x8 bhf = *reinterpret_cast<const bf16x8*>(&Kh_s[nf * 16 + c][kf * 32 + 8 * g]);
                bf16x8 blf = *reinterpret_cast<const bf16x8*>(&Kl_s[nf * 16 + c][kf * 32 + 8 * g]);
                s[nf] = MFMA_16x16x32(qa_h[kf], bhf, s[nf]);
                s[nf] = MFMA_16x16x32(qa_l[kf], bhf, s[nf]);
                s[nf] = MFMA_16x16x32(qa_h[kf], blf, s[nf]);
            }
        }

        // ---- online softmax. C layout: row = 4g+r, col = c (s[0]) / 16+c (s[1]).
#pragma unroll
        for (int r = 0; r < 4; ++r) {
            float s0 = s[0][r] * 0.125f;
            float s1 = s[1][r] * 0.125f;
            float t = fmaxf(s0, s1);
#pragma unroll
            for (int off = 1; off < 16; off <<= 1) t = fmaxf(t, __shfl_xor(t, off));
            float mnew = fmaxf(mrow[r], t);
            float corr = __expf(mrow[r] - mnew);
            float p0 = __expf(s0 - mnew);
            float p1 = __expf(s1 - mnew);
            float ps = p0 + p1;
#pragma unroll
            for (int off = 1; off < 16; off <<= 1) ps += __shfl_xor(ps, off);
            lrow[r] = lrow[r] * corr + ps;
            mrow[r] = mnew;
#pragma unroll
            for (int f = 0; f < 4; ++f) o[f][r] *= corr;
            P_s[w][g * 4 + r][c]      = f2bf(p0);
            P_s[w][g * 4 + r][16 + c] = f2bf(p1);
        }

        // ---- O += P V. A-frag of P: row c, k = 8g+j (contiguous -> b128 read).
        bf16x8 pa = *reinterpret_cast<const bf16x8*>(&P_s[w][c][8 * g]);
#pragma unroll
        for (int f = 0; f < 4; ++f) {
            bf16x8 bv;
#pragma unroll
            for (int j = 0; j < 8; ++j) bv[j] = (short)V_s[8 * g + j][f * 16 + c];
            o[f] = MFMA_16x16x32(pa, bv, o[f]);
        }
    }

    // ---- epilogue: divide by l, split to hi/lo bf16, write [b][q][h*64+d]
    const size_t xbase = ((size_t)b * NCTX + q0) * EMB + h * DH;
#pragma unroll
    for (int f = 0; f < 4; ++f) {
#pragma unroll
        for (int r = 0; r < 4; ++r) {
            float v = o[f][r] / lrow[r];
            uint16_t hv = f2bf(v);
            uint16_t lv = f2bf(v - bf2f(hv));
            size_t addr = xbase + (size_t)(g * 4 + r) * EMB + f * 16 + c;
            xh[addr] = hv;
            xl[addr] = lv;
        }
    }
}

// ---------- projection GEMM: Y[4096x768] = X @ W^T + bias (3-term split) ----------
// grid: (4096/64, 768/64), block 256. Wave w owns rows m0+w*16..+16, all 64 cols.
__global__ __launch_bounds__(256) void k_proj(
        const uint16_t* __restrict__ xh, const uint16_t* __restrict__ xl,
        const uint16_t* __restrict__ wh, const uint16_t* __restrict__ wl,
        const float* __restrict__ bias, float* __restrict__ out) {
    const int tid = threadIdx.x;
    const int w = tid >> 6;
    const int l = tid & 63;
    const int g = l >> 4;
    const int c = l & 15;
    const int m0 = blockIdx.x * 64 + w * 16;
    const int n0 = blockIdx.y * 64;

    __shared__ uint16_t Wh_s[64][40];
    __shared__ uint16_t Wl_s[64][40];

    f32x4 zero = {0.f, 0.f, 0.f, 0.f};
    f32x4 acc[4] = {zero, zero, zero, zero};

    const int srow = tid >> 2;   // 0..63
    const int sch  = tid & 3;    // 0..3

    for (int ks = 0; ks < EMB / 32; ++ks) {
        __syncthreads();
        const size_t woff = (size_t)(n0 + srow) * EMB + ks * 32 + sch * 8;
        *reinterpret_cast<bf16x8*>(&Wh_s[srow][sch * 8]) = *reinterpret_cast<const bf16x8*>(wh + woff);
        *reinterpret_cast<bf16x8*>(&Wl_s[srow][sch * 8]) = *reinterpret_cast<const bf16x8*>(wl + woff);
        __syncthreads();

        const size_t aoff = (size_t)(m0 + c) * EMB + ks * 32 + 8 * g;
        bf16x8 ah = *reinterpret_cast<const bf16x8*>(xh + aoff);
        bf16x8 al = *reinterpret_cast<const bf16x8*>(xl + aoff);
#pragma unroll
        for (int nf = 0; nf < 4; ++nf) {
            bf16x8 bhf = *reinterpret_cast<const bf16x8*>(&Wh_s[nf * 16 + c][8 * g]);
            bf16x8 blf = *reinterpret_cast<const bf16x8*>(&Wl_s[nf * 16 + c][8 * g]);
            acc[nf] = MFMA_16x16x32(ah, bhf, acc[nf]);
            acc[nf] = MFMA_16x16x32(al, bhf, acc[nf]);
            acc[nf] = MFMA_16x16x32(ah, blf, acc[nf]);
        }
    }

#pragma unroll
    for (int nf = 0; nf < 4; ++nf) {
#pragma unroll
        for (int r = 0; r < 4; ++r) {
            int row = m0 + g * 4 + r;
            int col = n0 + nf * 16 + c;
            out[(size_t)row * EMB + col] = acc[nf][r] + bias[col];
        }
    }
}

extern "C" void kernel_launch(void* const* d_in, const int* in_sizes, int n_in,
                              void* d_out, int out_size, void* d_ws, size_t ws_size,
                              hipStream_t stream) {
    const float* q    = (const float*)d_in[0];
    const float* k    = (const float*)d_in[1];
    const float* v    = (const float*)d_in[2];
    const float* pw   = (const float*)d_in[3];
    const float* pb   = (const float*)d_in[4];
    float* out = (float*)d_out;

    const size_t nqkv = (size_t)BATCH * HEADS * NCTX * DH;   // 3,145,728
    const size_t nx   = (size_t)BATCH * NCTX * EMB;          // 3,145,728
    const size_t nw   = (size_t)EMB * EMB;                   //   589,824

    uint8_t* ws = (uint8_t*)d_ws;
    uint16_t* qh = (uint16_t*)ws;              ws += nqkv * 2;
    uint16_t* ql = (uint16_t*)ws;              ws += nqkv * 2;
    uint16_t* kh = (uint16_t*)ws;              ws += nqkv * 2;
    uint16_t* kl = (uint16_t*)ws;              ws += nqkv * 2;
    uint16_t* vb = (uint16_t*)ws;              ws += nqkv * 2;
    uint16_t* xh = (uint16_t*)ws;              ws += nx * 2;
    uint16_t* xl = (uint16_t*)ws;              ws += nx * 2;
    uint16_t* wh = (uint16_t*)ws;              ws += nw * 2;
    uint16_t* wl = (uint16_t*)ws;              ws += nw * 2;

    // converts
    k_split<<<(int)(nqkv / 4 / 256), 256, 0, stream>>>(q, qh, ql, (int)(nqkv / 4));
    k_split<<<(int)(nqkv / 4 / 256), 256, 0, stream>>>(k, kh, kl, (int)(nqkv / 4));
    k_conv <<<(int)(nqkv / 4 / 256), 256, 0, stream>>>(v, vb, (int)(nqkv / 4));
    k_split<<<(int)(nw / 4 / 256),   256, 0, stream>>>(pw, wh, wl, (int)(nw / 4));

    // attention
    k_attn<<<dim3(NCTX / 64, BATCH * HEADS), 256, 0, stream>>>(qh, ql, kh, kl, vb, xh, xl);

    // projection
    k_proj<<<dim3((BATCH * NCTX) / 64, EMB / 64), 256, 0, stream>>>(xh, xl, wh, wl, pb, out);
}

// Round 2
// 134.679 us; speedup vs baseline: 1.7815x; 1.7815x over previous
//
#include <hip/hip_runtime.h>
#include <cstdint>

typedef short bf16x8 __attribute__((ext_vector_type(8)));
typedef float f32x4 __attribute__((ext_vector_type(4)));
typedef uint16_t u16x4 __attribute__((ext_vector_type(4)));

#define MFMA_16x16x32(a, b, c) __builtin_amdgcn_mfma_f32_16x16x32_bf16((a), (b), (c), 0, 0, 0)

static constexpr int BATCH = 2;
static constexpr int HEADS = 12;
static constexpr int NCTX  = 2048;
static constexpr int DH    = 64;
static constexpr int EMB   = 768;

// ---------- bf16 helpers (raw-bit, RN rounding) ----------
__device__ __forceinline__ uint16_t f2bf(float x) {
    uint32_t u = __float_as_uint(x);
    u += 0x7FFFu + ((u >> 16) & 1u);
    return (uint16_t)(u >> 16);
}
__device__ __forceinline__ float bf2f(uint16_t h) {
    return __uint_as_float(((uint32_t)h) << 16);
}

// ---------- split convert (optionally pre-scaled) ----------
__global__ void k_split(const float* __restrict__ src, uint16_t* __restrict__ hi,
                        uint16_t* __restrict__ lo, int n4, float scale) {
    int i = blockIdx.x * blockDim.x + threadIdx.x;
    if (i >= n4) return;
    float4 v = reinterpret_cast<const float4*>(src)[i];
    v.x *= scale; v.y *= scale; v.z *= scale; v.w *= scale;
    uint16_t h0 = f2bf(v.x), h1 = f2bf(v.y), h2 = f2bf(v.z), h3 = f2bf(v.w);
    u16x4 hv = {h0, h1, h2, h3};
    u16x4 lv = {f2bf(v.x - bf2f(h0)), f2bf(v.y - bf2f(h1)),
                f2bf(v.z - bf2f(h2)), f2bf(v.w - bf2f(h3))};
    reinterpret_cast<u16x4*>(hi)[i] = hv;
    reinterpret_cast<u16x4*>(lo)[i] = lv;
}

// ---------- V transpose+convert: [bh][n][64] fp32 -> [bh][64][n] bf16 ----------
__global__ __launch_bounds__(256) void k_vt(const float* __restrict__ v,
                                            uint16_t* __restrict__ vt) {
    const int bh = blockIdx.y;
    const int n0 = blockIdx.x * 64;
    const int t  = threadIdx.x;
    __shared__ uint16_t tileT[64][72];   // [d][n_local]

    const int r  = t >> 2;          // n-row within tile (0..63)
    const int cc = (t & 3) * 16;    // d-col base
    const float* vp = v + ((size_t)bh * NCTX + n0 + r) * DH + cc;
#pragma unroll
    for (int u = 0; u < 4; ++u) {
        float4 x = reinterpret_cast<const float4*>(vp)[u];
        tileT[cc + 4 * u + 0][r] = f2bf(x.x);
        tileT[cc + 4 * u + 1][r] = f2bf(x.y);
        tileT[cc + 4 * u + 2][r] = f2bf(x.z);
        tileT[cc + 4 * u + 3][r] = f2bf(x.w);
    }
    __syncthreads();
    const int d  = t >> 2;          // d-row (0..63)
    const int nc = (t & 3) * 16;    // n chunk
    uint16_t* op = vt + ((size_t)bh * DH + d) * NCTX + n0 + nc;
#pragma unroll
    for (int u = 0; u < 2; ++u) {
        bf16x8 x = *reinterpret_cast<const bf16x8*>(&tileT[d][nc + 8 * u]);
        *reinterpret_cast<bf16x8*>(op + 8 * u) = x;
    }
}

// ---------- flash attention ----------
// grid: (NCTX/64, BATCH*HEADS), block 256 (4 waves). Wave owns 16 q-rows.
// KVBLK=64, register-prefetch double buffering, deferred-max online softmax.
__global__ __launch_bounds__(256) void k_attn(
        const uint16_t* __restrict__ qh, const uint16_t* __restrict__ ql,
        const uint16_t* __restrict__ kh, const uint16_t* __restrict__ kl,
        const uint16_t* __restrict__ vt,
        uint16_t* __restrict__ xh, uint16_t* __restrict__ xl) {
    const int bh = blockIdx.y;
    const int b  = bh / HEADS;
    const int h  = bh % HEADS;
    const int tid = threadIdx.x;
    const int w = tid >> 6;
    const int l = tid & 63;
    const int g = l >> 4;    // 16-lane group 0..3
    const int c = l & 15;

    __shared__ uint16_t Kh_s[64][72];
    __shared__ uint16_t Kl_s[64][72];
    __shared__ uint16_t Vt_s[64][72];   // [d][kv]
    __shared__ uint16_t P_s [4][16][72];

    const int q0 = blockIdx.x * 64 + w * 16;

    // Q fragments (Q was pre-scaled by 0.125 at split time)
    const size_t qoff = ((size_t)bh * NCTX + q0 + c) * DH + 8 * g;
    bf16x8 qa_h[2], qa_l[2];
    qa_h[0] = *reinterpret_cast<const bf16x8*>(qh + qoff);
    qa_h[1] = *reinterpret_cast<const bf16x8*>(qh + qoff + 32);
    qa_l[0] = *reinterpret_cast<const bf16x8*>(ql + qoff);
    qa_l[1] = *reinterpret_cast<const bf16x8*>(ql + qoff + 32);

    f32x4 zero = {0.f, 0.f, 0.f, 0.f};
    f32x4 o[4] = {zero, zero, zero, zero};
    float mrow[4] = {-1e30f, -1e30f, -1e30f, -1e30f};
    float lrow[4] = {0.f, 0.f, 0.f, 0.f};

    // staging decomposition: 256 thr -> 32 rows x 8 chunks, two row-passes
    const int srow = tid >> 3;      // 0..31
    const int sch  = tid & 7;       // 0..7

    const uint16_t* kh_b = kh + (size_t)bh * NCTX * DH + srow * DH + sch * 8;
    const uint16_t* kl_b = kl + (size_t)bh * NCTX * DH + srow * DH + sch * 8;
    const uint16_t* vt_b = vt + (size_t)bh * DH * NCTX + srow * NCTX + sch * 8;

    // prologue: stage tile 0
    {
        bf16x8 a0 = *reinterpret_cast<const bf16x8*>(kh_b);
        bf16x8 a1 = *reinterpret_cast<const bf16x8*>(kh_b + 32 * DH);
        bf16x8 b0 = *reinterpret_cast<const bf16x8*>(kl_b);
        bf16x8 b1 = *reinterpret_cast<const bf16x8*>(kl_b + 32 * DH);
        bf16x8 v0 = *reinterpret_cast<const bf16x8*>(vt_b);
        bf16x8 v1 = *reinterpret_cast<const bf16x8*>(vt_b + 32 * NCTX);
        *reinterpret_cast<bf16x8*>(&Kh_s[srow][sch * 8])      = a0;
        *reinterpret_cast<bf16x8*>(&Kh_s[srow + 32][sch * 8]) = a1;
        *reinterpret_cast<bf16x8*>(&Kl_s[srow][sch * 8])      = b0;
        *reinterpret_cast<bf16x8*>(&Kl_s[srow + 32][sch * 8]) = b1;
        *reinterpret_cast<bf16x8*>(&Vt_s[srow][sch * 8])      = v0;
        *reinterpret_cast<bf16x8*>(&Vt_s[srow + 32][sch * 8]) = v1;
    }
    __syncthreads();

    for (int t = 0; t < NCTX / 64; ++t) {
        // issue next-tile loads early (hide latency under compute)
        bf16x8 nkh0, nkh1, nkl0, nkl1, nv0, nv1;
        const bool pf = (t + 1) < NCTX / 64;
        if (pf) {
            const size_t ko = (size_t)(t + 1) * 64 * DH;
            const size_t vo = (size_t)(t + 1) * 64;
            nkh0 = *reinterpret_cast<const bf16x8*>(kh_b + ko);
            nkh1 = *reinterpret_cast<const bf16x8*>(kh_b + ko + 32 * DH);
            nkl0 = *reinterpret_cast<const bf16x8*>(kl_b + ko);
            nkl1 = *reinterpret_cast<const bf16x8*>(kl_b + ko + 32 * DH);
            nv0  = *reinterpret_cast<const bf16x8*>(vt_b + vo);
            nv1  = *reinterpret_cast<const bf16x8*>(vt_b + vo + 32 * NCTX);
        }

        // ---- S = Q K^T (3-term split). s[nf] covers kv cols nf*16..+16
        f32x4 s[4] = {zero, zero, zero, zero};
#pragma unroll
        for (int nf = 0; nf < 4; ++nf) {
#pragma unroll
            for (int kf = 0; kf < 2; ++kf) {
                bf16x8 bhf = *reinterpret_cast<const bf16x8*>(&Kh_s[nf * 16 + c][kf * 32 + 8 * g]);
                bf16x8 blf = *reinterpret_cast<const bf16x8*>(&Kl_s[nf * 16 + c][kf * 32 + 8 * g]);
                s[nf] = MFMA_16x16x32(qa_h[kf], bhf, s[nf]);
                s[nf] = MFMA_16x16x32(qa_l[kf], bhf, s[nf]);
                s[nf] = MFMA_16x16x32(qa_h[kf], blf, s[nf]);
            }
        }

        // ---- online softmax with deferred max (THR=8)
        float smax[4];
#pragma unroll
        for (int r = 0; r < 4; ++r)
            smax[r] = fmaxf(fmaxf(s[0][r], s[1][r]), fmaxf(s[2][r], s[3][r]));
        bool ok = true;
#pragma unroll
        for (int r = 0; r < 4; ++r) ok &= (smax[r] <= mrow[r] + 8.0f);
        if (!__all((int)ok)) {
#pragma unroll
            for (int r = 0; r < 4; ++r) {
                float t2 = smax[r];
#pragma unroll
                for (int off = 1; off < 16; off <<= 1) t2 = fmaxf(t2, __shfl_xor(t2, off));
                float mnew = fmaxf(mrow[r], t2);
                float corr = __expf(mrow[r] - mnew);
                mrow[r] = mnew;
                lrow[r] *= corr;
#pragma unroll
                for (int f = 0; f < 4; ++f) o[f][r] *= corr;
            }
        }
#pragma unroll
        for (int r = 0; r < 4; ++r) {
#pragma unroll
            for (int nf = 0; nf < 4; ++nf) {
                float p = __expf(s[nf][r] - mrow[r]);
                lrow[r] += p;
                P_s[w][g * 4 + r][nf * 16 + c] = f2bf(p);
            }
        }

        // ---- O += P V (Vt_s gives contiguous B-fragments)
        bf16x8 pa0 = *reinterpret_cast<const bf16x8*>(&P_s[w][c][8 * g]);
        bf16x8 pa1 = *reinterpret_cast<const bf16x8*>(&P_s[w][c][32 + 8 * g]);
#pragma unroll
        for (int f = 0; f < 4; ++f) {
            bf16x8 b0 = *reinterpret_cast<const bf16x8*>(&Vt_s[f * 16 + c][8 * g]);
            bf16x8 b1 = *reinterpret_cast<const bf16x8*>(&Vt_s[f * 16 + c][32 + 8 * g]);
            o[f] = MFMA_16x16x32(pa0, b0, o[f]);
            o[f] = MFMA_16x16x32(pa1, b1, o[f]);
        }

        __syncthreads();   // all waves done reading this tile
        if (pf) {
            *reinterpret_cast<bf16x8*>(&Kh_s[srow][sch * 8])      = nkh0;
            *reinterpret_cast<bf16x8*>(&Kh_s[srow + 32][sch * 8]) = nkh1;
            *reinterpret_cast<bf16x8*>(&Kl_s[srow][sch * 8])      = nkl0;
            *reinterpret_cast<bf16x8*>(&Kl_s[srow + 32][sch * 8]) = nkl1;
            *reinterpret_cast<bf16x8*>(&Vt_s[srow][sch * 8])      = nv0;
            *reinterpret_cast<bf16x8*>(&Vt_s[srow + 32][sch * 8]) = nv1;
        }
        __syncthreads();   // next tile visible
    }

    // ---- epilogue: reduce l across the 16-lane group, normalize, split, store
#pragma unroll
    for (int r = 0; r < 4; ++r) {
        float t2 = lrow[r];
#pragma unroll
        for (int off = 1; off < 16; off <<= 1) t2 += __shfl_xor(t2, off);
        lrow[r] = 1.0f / t2;
    }
    const size_t xbase = ((size_t)b * NCTX + q0) * EMB + h * DH;
#pragma unroll
    for (int f = 0; f < 4; ++f) {
#pragma unroll
        for (int r = 0; r < 4; ++r) {
            float v = o[f][r] * lrow[r];
            uint16_t hv = f2bf(v);
            uint16_t lv = f2bf(v - bf2f(hv));
            size_t addr = xbase + (size_t)(g * 4 + r) * EMB + f * 16 + c;
            xh[addr] = hv;
            xl[addr] = lv;
        }
    }
}

// ---------- projection GEMM: Y[4096x768] = X @ W^T + bias (3-term split) ----------
__global__ __launch_bounds__(256) void k_proj(
        const uint16_t* __restrict__ xh, const uint16_t* __restrict__ xl,
        const uint16_t* __restrict__ wh, const uint16_t* __restrict__ wl,
        const float* __restrict__ bias, float* __restrict__ out) {
    const int tid = threadIdx.x;
    const int w = tid >> 6;
    const int l = tid & 63;
    const int g = l >> 4;
    const int c = l & 15;
    const int m0 = blockIdx.x * 64 + w * 16;
    const int n0 = blockIdx.y * 64;

    __shared__ uint16_t Wh_s[64][40];
    __shared__ uint16_t Wl_s[64][40];

    f32x4 zero = {0.f, 0.f, 0.f, 0.f};
    f32x4 acc[4] = {zero, zero, zero, zero};

    const int srow = tid >> 2;   // 0..63
    const int sch  = tid & 3;    // 0..3

    for (int ks = 0; ks < EMB / 32; ++ks) {
        __syncthreads();
        const size_t woff = (size_t)(n0 + srow) * EMB + ks * 32 + sch * 8;
        *reinterpret_cast<bf16x8*>(&Wh_s[srow][sch * 8]) = *reinterpret_cast<const bf16x8*>(wh + woff);
        *reinterpret_cast<bf16x8*>(&Wl_s[srow][sch * 8]) = *reinterpret_cast<const bf16x8*>(wl + woff);
        __syncthreads();

        const size_t aoff = (size_t)(m0 + c) * EMB + ks * 32 + 8 * g;
        bf16x8 ah = *reinterpret_cast<const bf16x8*>(xh + aoff);
        bf16x8 al = *reinterpret_cast<const bf16x8*>(xl + aoff);
#pragma unroll
        for (int nf = 0; nf < 4; ++nf) {
            bf16x8 bhf = *reinterpret_cast<const bf16x8*>(&Wh_s[nf * 16 + c][8 * g]);
            bf16x8 blf = *reinterpret_cast<const bf16x8*>(&Wl_s[nf * 16 + c][8 * g]);
            acc[nf] = MFMA_16x16x32(ah, bhf, acc[nf]);
            acc[nf] = MFMA_16x16x32(al, bhf, acc[nf]);
            acc[nf] = MFMA_16x16x32(ah, blf, acc[nf]);
        }
    }

#pragma unroll
    for (int nf = 0; nf < 4; ++nf) {
#pragma unroll
        for (int r = 0; r < 4; ++r) {
            int row = m0 + g * 4 + r;
            int col = n0 + nf * 16 + c;
            out[(size_t)row * EMB + col] = acc[nf][r] + bias[col];
        }
    }
}

extern "C" void kernel_launch(void* const* d_in, const int* in_sizes, int n_in,
                              void* d_out, int out_size, void* d_ws, size_t ws_size,
                              hipStream_t stream) {
    const float* q    = (const float*)d_in[0];
    const float* k    = (const float*)d_in[1];
    const float* v    = (const float*)d_in[2];
    const float* pw   = (const float*)d_in[3];
    const float* pb   = (const float*)d_in[4];
    float* out = (float*)d_out;

    const size_t nqkv = (size_t)BATCH * HEADS * NCTX * DH;   // 3,145,728
    const size_t nx   = (size_t)BATCH * NCTX * EMB;          // 3,145,728
    const size_t nw   = (size_t)EMB * EMB;                   //   589,824

    uint8_t* ws = (uint8_t*)d_ws;
    uint16_t* qh = (uint16_t*)ws;              ws += nqkv * 2;
    uint16_t* ql = (uint16_t*)ws;              ws += nqkv * 2;
    uint16_t* kh = (uint16_t*)ws;              ws += nqkv * 2;
    uint16_t* kl = (uint16_t*)ws;              ws += nqkv * 2;
    uint16_t* vt = (uint16_t*)ws;              ws += nqkv * 2;
    uint16_t* xh = (uint16_t*)ws;              ws += nx * 2;
    uint16_t* xl = (uint16_t*)ws;              ws += nx * 2;
    uint16_t* wh = (uint16_t*)ws;              ws += nw * 2;
    uint16_t* wl = (uint16_t*)ws;              ws += nw * 2;

    // converts (Q pre-scaled by softmax scale)
    k_split<<<(int)(nqkv / 4 / 256), 256, 0, stream>>>(q, qh, ql, (int)(nqkv / 4), 0.125f);
    k_split<<<(int)(nqkv / 4 / 256), 256, 0, stream>>>(k, kh, kl, (int)(nqkv / 4), 1.0f);
    k_split<<<(int)(nw / 4 / 256),   256, 0, stream>>>(pw, wh, wl, (int)(nw / 4), 1.0f);
    k_vt<<<dim3(NCTX / 64, BATCH * HEADS), 256, 0, stream>>>(v, vt);

    // attention
    k_attn<<<dim3(NCTX / 64, BATCH * HEADS), 256, 0, stream>>>(qh, ql, kh, kl, vt, xh, xl);

    // projection
    k_proj<<<dim3((BATCH * NCTX) / 64, EMB / 64), 256, 0, stream>>>(xh, xl, wh, wl, pb, out);
}

// Round 3
// 123.294 us; speedup vs baseline: 1.9460x; 1.0923x over previous
//
#include <hip/hip_runtime.h>
#include <cstdint>

typedef short bf16x8 __attribute__((ext_vector_type(8)));
typedef float f32x4 __attribute__((ext_vector_type(4)));
typedef uint16_t u16x4 __attribute__((ext_vector_type(4)));

#define MFMA_16x16x32(a, b, c) __builtin_amdgcn_mfma_f32_16x16x32_bf16((a), (b), (c), 0, 0, 0)

static constexpr int BATCH = 2;
static constexpr int HEADS = 12;
static constexpr int NCTX  = 2048;
static constexpr int DH    = 64;
static constexpr int EMB   = 768;

// 0.125 * log2(e): Q pre-scale so softmax runs in exp2 domain
static constexpr float QSCALE = 0.125f * 1.44269504088896340736f;

// ---------- bf16 helpers (raw-bit, RN rounding) ----------
__device__ __forceinline__ uint16_t f2bf(float x) {
    uint32_t u = __float_as_uint(x);
    u += 0x7FFFu + ((u >> 16) & 1u);
    return (uint16_t)(u >> 16);
}
__device__ __forceinline__ float bf2f(uint16_t h) {
    return __uint_as_float(((uint32_t)h) << 16);
}
__device__ __forceinline__ uint32_t cvt_pk_bf16(float lo, float hi) {
    uint32_t r;
    asm("v_cvt_pk_bf16_f32 %0, %1, %2" : "=v"(r) : "v"(lo), "v"(hi));
    return r;
}

// ---------- merged Q/K split convert (blockIdx.y: 0=Q pre-scaled, 1=K) ----------
__global__ void k_splitqk(const float* __restrict__ q, const float* __restrict__ k,
                          uint16_t* __restrict__ qh, uint16_t* __restrict__ ql,
                          uint16_t* __restrict__ kh, uint16_t* __restrict__ kl, int n4) {
    int i = blockIdx.x * blockDim.x + threadIdx.x;
    if (i >= n4) return;
    const bool isK = blockIdx.y != 0;
    const float* src = isK ? k : q;
    uint16_t* hi = isK ? kh : qh;
    uint16_t* lo = isK ? kl : ql;
    const float scale = isK ? 1.0f : QSCALE;
    float4 v = reinterpret_cast<const float4*>(src)[i];
    v.x *= scale; v.y *= scale; v.z *= scale; v.w *= scale;
    uint16_t h0 = f2bf(v.x), h1 = f2bf(v.y), h2 = f2bf(v.z), h3 = f2bf(v.w);
    u16x4 hv = {h0, h1, h2, h3};
    u16x4 lv = {f2bf(v.x - bf2f(h0)), f2bf(v.y - bf2f(h1)),
                f2bf(v.z - bf2f(h2)), f2bf(v.w - bf2f(h3))};
    reinterpret_cast<u16x4*>(hi)[i] = hv;
    reinterpret_cast<u16x4*>(lo)[i] = lv;
}

// ---------- plain split (for W) ----------
__global__ void k_split(const float* __restrict__ src, uint16_t* __restrict__ hi,
                        uint16_t* __restrict__ lo, int n4) {
    int i = blockIdx.x * blockDim.x + threadIdx.x;
    if (i >= n4) return;
    float4 v = reinterpret_cast<const float4*>(src)[i];
    uint16_t h0 = f2bf(v.x), h1 = f2bf(v.y), h2 = f2bf(v.z), h3 = f2bf(v.w);
    u16x4 hv = {h0, h1, h2, h3};
    u16x4 lv = {f2bf(v.x - bf2f(h0)), f2bf(v.y - bf2f(h1)),
                f2bf(v.z - bf2f(h2)), f2bf(v.w - bf2f(h3))};
    reinterpret_cast<u16x4*>(hi)[i] = hv;
    reinterpret_cast<u16x4*>(lo)[i] = lv;
}

// ---------- V transpose+convert: [bh][n][64] fp32 -> [bh][64][n] bf16 ----------
__global__ __launch_bounds__(256) void k_vt(const float* __restrict__ v,
                                            uint16_t* __restrict__ vt) {
    const int bh = blockIdx.y;
    const int n0 = blockIdx.x * 64;
    const int t  = threadIdx.x;
    __shared__ uint16_t tileT[64][72];   // [d][n_local]

    const int r  = t >> 2;          // n-row within tile (0..63)
    const int cc = (t & 3) * 16;    // d-col base
    const float* vp = v + ((size_t)bh * NCTX + n0 + r) * DH + cc;
#pragma unroll
    for (int u = 0; u < 4; ++u) {
        float4 x = reinterpret_cast<const float4*>(vp)[u];
        tileT[cc + 4 * u + 0][r] = f2bf(x.x);
        tileT[cc + 4 * u + 1][r] = f2bf(x.y);
        tileT[cc + 4 * u + 2][r] = f2bf(x.z);
        tileT[cc + 4 * u + 3][r] = f2bf(x.w);
    }
    __syncthreads();
    const int d  = t >> 2;          // d-row (0..63)
    const int nc = (t & 3) * 16;    // n chunk
    uint16_t* op = vt + ((size_t)bh * DH + d) * NCTX + n0 + nc;
#pragma unroll
    for (int u = 0; u < 2; ++u) {
        bf16x8 x = *reinterpret_cast<const bf16x8*>(&tileT[d][nc + 8 * u]);
        *reinterpret_cast<bf16x8*>(op + 8 * u) = x;
    }
}

// ---------- flash attention ----------
// grid: (NCTX/64, BATCH*HEADS), block 256 (4 waves). Wave owns 16 q-rows.
// Swapped QK^T (S^T in regs: lane holds q=c, kv=16nf+4g+r) -> cheap softmax,
// vectorized P writes, exp2 domain, deferred max, reg-prefetch double buffer.
__global__ __launch_bounds__(256) void k_attn(
        const uint16_t* __restrict__ qh, const uint16_t* __restrict__ ql,
        const uint16_t* __restrict__ kh, const uint16_t* __restrict__ kl,
        const uint16_t* __restrict__ vt,
        uint16_t* __restrict__ xh, uint16_t* __restrict__ xl) {
    const int bh = blockIdx.y;
    const int b  = bh / HEADS;
    const int h  = bh % HEADS;
    const int tid = threadIdx.x;
    const int w = tid >> 6;
    const int l = tid & 63;
    const int g = l >> 4;    // 16-lane group 0..3
    const int c = l & 15;

    __shared__ uint16_t Kh_s[64][72];
    __shared__ uint16_t Kl_s[64][72];
    __shared__ uint16_t Vt_s[64][72];   // [d][kv]
    __shared__ uint16_t P_s [4][16][72];  // [wave][q][kv]

    const int q0 = blockIdx.x * 64 + w * 16;

    // Q fragments (pre-scaled by 0.125*log2e at split time)
    const size_t qoff = ((size_t)bh * NCTX + q0 + c) * DH + 8 * g;
    bf16x8 qa_h[2], qa_l[2];
    qa_h[0] = *reinterpret_cast<const bf16x8*>(qh + qoff);
    qa_h[1] = *reinterpret_cast<const bf16x8*>(qh + qoff + 32);
    qa_l[0] = *reinterpret_cast<const bf16x8*>(ql + qoff);
    qa_l[1] = *reinterpret_cast<const bf16x8*>(ql + qoff + 32);

    f32x4 zero = {0.f, 0.f, 0.f, 0.f};
    f32x4 o[4] = {zero, zero, zero, zero};
    float m = -1e30f;     // running max (log2 units), per q=c (uniform across groups)
    float lsum = 0.f;     // lane-partial softmax denominator for q=c

    // staging decomposition: 256 thr -> 32 rows x 8 chunks, two row-passes
    const int srow = tid >> 3;      // 0..31
    const int sch  = tid & 7;       // 0..7

    const uint16_t* kh_b = kh + (size_t)bh * NCTX * DH + srow * DH + sch * 8;
    const uint16_t* kl_b = kl + (size_t)bh * NCTX * DH + srow * DH + sch * 8;
    const uint16_t* vt_b = vt + (size_t)bh * DH * NCTX + srow * NCTX + sch * 8;

    // prologue: stage tile 0
    {
        bf16x8 a0 = *reinterpret_cast<const bf16x8*>(kh_b);
        bf16x8 a1 = *reinterpret_cast<const bf16x8*>(kh_b + 32 * DH);
        bf16x8 b0 = *reinterpret_cast<const bf16x8*>(kl_b);
        bf16x8 b1 = *reinterpret_cast<const bf16x8*>(kl_b + 32 * DH);
        bf16x8 v0 = *reinterpret_cast<const bf16x8*>(vt_b);
        bf16x8 v1 = *reinterpret_cast<const bf16x8*>(vt_b + 32 * NCTX);
        *reinterpret_cast<bf16x8*>(&Kh_s[srow][sch * 8])      = a0;
        *reinterpret_cast<bf16x8*>(&Kh_s[srow + 32][sch * 8]) = a1;
        *reinterpret_cast<bf16x8*>(&Kl_s[srow][sch * 8])      = b0;
        *reinterpret_cast<bf16x8*>(&Kl_s[srow + 32][sch * 8]) = b1;
        *reinterpret_cast<bf16x8*>(&Vt_s[srow][sch * 8])      = v0;
        *reinterpret_cast<bf16x8*>(&Vt_s[srow + 32][sch * 8]) = v1;
    }
    __syncthreads();

    for (int t = 0; t < NCTX / 64; ++t) {
        // issue next-tile loads early (hide latency under compute)
        bf16x8 nkh0, nkh1, nkl0, nkl1, nv0, nv1;
        const bool pf = (t + 1) < NCTX / 64;
        if (pf) {
            const size_t ko = (size_t)(t + 1) * 64 * DH;
            const size_t vo = (size_t)(t + 1) * 64;
            nkh0 = *reinterpret_cast<const bf16x8*>(kh_b + ko);
            nkh1 = *reinterpret_cast<const bf16x8*>(kh_b + ko + 32 * DH);
            nkl0 = *reinterpret_cast<const bf16x8*>(kl_b + ko);
            nkl1 = *reinterpret_cast<const bf16x8*>(kl_b + ko + 32 * DH);
            nv0  = *reinterpret_cast<const bf16x8*>(vt_b + vo);
            nv1  = *reinterpret_cast<const bf16x8*>(vt_b + vo + 32 * NCTX);
        }

        // ---- S^T = (K Q^T) (3-term split). s[nf][r] = S[kv=16nf+4g+r][q=c]
        f32x4 s[4] = {zero, zero, zero, zero};
        __builtin_amdgcn_s_setprio(1);
#pragma unroll
        for (int nf = 0; nf < 4; ++nf) {
#pragma unroll
            for (int kf = 0; kf < 2; ++kf) {
                bf16x8 bhf = *reinterpret_cast<const bf16x8*>(&Kh_s[nf * 16 + c][kf * 32 + 8 * g]);
                bf16x8 blf = *reinterpret_cast<const bf16x8*>(&Kl_s[nf * 16 + c][kf * 32 + 8 * g]);
                s[nf] = MFMA_16x16x32(bhf, qa_h[kf], s[nf]);
                s[nf] = MFMA_16x16x32(blf, qa_h[kf], s[nf]);
                s[nf] = MFMA_16x16x32(bhf, qa_l[kf], s[nf]);
            }
        }
        __builtin_amdgcn_s_setprio(0);

        // ---- softmax (log2 domain). Row (per-q) reduce: in-lane + 2 shfls.
        float smax = s[0][0];
#pragma unroll
        for (int nf = 0; nf < 4; ++nf)
#pragma unroll
            for (int r = 0; r < 4; ++r) smax = fmaxf(smax, s[nf][r]);
        smax = fmaxf(smax, __shfl_xor(smax, 16));
        smax = fmaxf(smax, __shfl_xor(smax, 32));

        // deferred max (THR = 11 in log2 units ~= e^8)
        if (!__all(smax <= m + 11.0f)) {
            float mnew = fmaxf(m, smax);
            float corr = __builtin_amdgcn_exp2f(m - mnew);
            m = mnew;
            lsum *= corr;
#pragma unroll
            for (int r = 0; r < 4; ++r) {
                float cr = __shfl(corr, 4 * g + r);   // corr for q-local 4g+r
#pragma unroll
                for (int f = 0; f < 4; ++f) o[f][r] *= cr;
            }
        }

        // p = exp2(s - m); pack pairs and write 4 contiguous kv per lane (b64)
#pragma unroll
        for (int nf = 0; nf < 4; ++nf) {
            float p0 = __builtin_amdgcn_exp2f(s[nf][0] - m);
            float p1 = __builtin_amdgcn_exp2f(s[nf][1] - m);
            float p2 = __builtin_amdgcn_exp2f(s[nf][2] - m);
            float p3 = __builtin_amdgcn_exp2f(s[nf][3] - m);
            lsum += (p0 + p1) + (p2 + p3);
            uint2 pk;
            pk.x = cvt_pk_bf16(p0, p1);
            pk.y = cvt_pk_bf16(p2, p3);
            *reinterpret_cast<uint2*>(&P_s[w][c][16 * nf + 4 * g]) = pk;
        }

        // ---- O += P V (Vt_s gives contiguous B-fragments)
        bf16x8 pa0 = *reinterpret_cast<const bf16x8*>(&P_s[w][c][8 * g]);
        bf16x8 pa1 = *reinterpret_cast<const bf16x8*>(&P_s[w][c][32 + 8 * g]);
        __builtin_amdgcn_s_setprio(1);
#pragma unroll
        for (int f = 0; f < 4; ++f) {
            bf16x8 b0 = *reinterpret_cast<const bf16x8*>(&Vt_s[f * 16 + c][8 * g]);
            bf16x8 b1 = *reinterpret_cast<const bf16x8*>(&Vt_s[f * 16 + c][32 + 8 * g]);
            o[f] = MFMA_16x16x32(pa0, b0, o[f]);
            o[f] = MFMA_16x16x32(pa1, b1, o[f]);
        }
        __builtin_amdgcn_s_setprio(0);

        __syncthreads();   // all waves done reading this tile
        if (pf) {
            *reinterpret_cast<bf16x8*>(&Kh_s[srow][sch * 8])      = nkh0;
            *reinterpret_cast<bf16x8*>(&Kh_s[srow + 32][sch * 8]) = nkh1;
            *reinterpret_cast<bf16x8*>(&Kl_s[srow][sch * 8])      = nkl0;
            *reinterpret_cast<bf16x8*>(&Kl_s[srow + 32][sch * 8]) = nkl1;
            *reinterpret_cast<bf16x8*>(&Vt_s[srow][sch * 8])      = nv0;
            *reinterpret_cast<bf16x8*>(&Vt_s[srow + 32][sch * 8]) = nv1;
        }
        __syncthreads();   // next tile visible
    }

    // ---- epilogue: reduce l over the 4 groups, normalize, split, store
    lsum += __shfl_xor(lsum, 16);
    lsum += __shfl_xor(lsum, 32);
    const float linv = 1.0f / lsum;

    const size_t xbase = ((size_t)b * NCTX + q0) * EMB + h * DH;
#pragma unroll
    for (int r = 0; r < 4; ++r) {
        float lr = __shfl(linv, 4 * g + r);   // 1/l for q-local 4g+r
#pragma unroll
        for (int f = 0; f < 4; ++f) {
            float v = o[f][r] * lr;
            uint16_t hv = f2bf(v);
            uint16_t lv2 = f2bf(v - bf2f(hv));
            size_t addr = xbase + (size_t)(4 * g + r) * EMB + f * 16 + c;
            xh[addr] = hv;
            xl[addr] = lv2;
        }
    }
}

// ---------- projection GEMM: Y[4096x768] = X @ W^T + bias (3-term split) ----------
__global__ __launch_bounds__(256) void k_proj(
        const uint16_t* __restrict__ xh, const uint16_t* __restrict__ xl,
        const uint16_t* __restrict__ wh, const uint16_t* __restrict__ wl,
        const float* __restrict__ bias, float* __restrict__ out) {
    const int tid = threadIdx.x;
    const int w = tid >> 6;
    const int l = tid & 63;
    const int g = l >> 4;
    const int c = l & 15;
    const int m0 = blockIdx.x * 64 + w * 16;
    const int n0 = blockIdx.y * 64;

    __shared__ uint16_t Wh_s[64][40];
    __shared__ uint16_t Wl_s[64][40];

    f32x4 zero = {0.f, 0.f, 0.f, 0.f};
    f32x4 acc[4] = {zero, zero, zero, zero};

    const int srow = tid >> 2;   // 0..63
    const int sch  = tid & 3;    // 0..3

    for (int ks = 0; ks < EMB / 32; ++ks) {
        __syncthreads();
        const size_t woff = (size_t)(n0 + srow) * EMB + ks * 32 + sch * 8;
        *reinterpret_cast<bf16x8*>(&Wh_s[srow][sch * 8]) = *reinterpret_cast<const bf16x8*>(wh + woff);
        *reinterpret_cast<bf16x8*>(&Wl_s[srow][sch * 8]) = *reinterpret_cast<const bf16x8*>(wl + woff);
        __syncthreads();

        const size_t aoff = (size_t)(m0 + c) * EMB + ks * 32 + 8 * g;
        bf16x8 ah = *reinterpret_cast<const bf16x8*>(xh + aoff);
        bf16x8 al = *reinterpret_cast<const bf16x8*>(xl + aoff);
#pragma unroll
        for (int nf = 0; nf < 4; ++nf) {
            bf16x8 bhf = *reinterpret_cast<const bf16x8*>(&Wh_s[nf * 16 + c][8 * g]);
            bf16x8 blf = *reinterpret_cast<const bf16x8*>(&Wl_s[nf * 16 + c][8 * g]);
            acc[nf] = MFMA_16x16x32(ah, bhf, acc[nf]);
            acc[nf] = MFMA_16x16x32(al, bhf, acc[nf]);
            acc[nf] = MFMA_16x16x32(ah, blf, acc[nf]);
        }
    }

#pragma unroll
    for (int nf = 0; nf < 4; ++nf) {
#pragma unroll
        for (int r = 0; r < 4; ++r) {
            int row = m0 + g * 4 + r;
            int col = n0 + nf * 16 + c;
            out[(size_t)row * EMB + col] = acc[nf][r] + bias[col];
        }
    }
}

extern "C" void kernel_launch(void* const* d_in, const int* in_sizes, int n_in,
                              void* d_out, int out_size, void* d_ws, size_t ws_size,
                              hipStream_t stream) {
    const float* q    = (const float*)d_in[0];
    const float* k    = (const float*)d_in[1];
    const float* v    = (const float*)d_in[2];
    const float* pw   = (const float*)d_in[3];
    const float* pb   = (const float*)d_in[4];
    float* out = (float*)d_out;

    const size_t nqkv = (size_t)BATCH * HEADS * NCTX * DH;   // 3,145,728
    const size_t nx   = (size_t)BATCH * NCTX * EMB;          // 3,145,728
    const size_t nw   = (size_t)EMB * EMB;                   //   589,824

    uint8_t* ws = (uint8_t*)d_ws;
    uint16_t* qh = (uint16_t*)ws;              ws += nqkv * 2;
    uint16_t* ql = (uint16_t*)ws;              ws += nqkv * 2;
    uint16_t* kh = (uint16_t*)ws;              ws += nqkv * 2;
    uint16_t* kl = (uint16_t*)ws;              ws += nqkv * 2;
    uint16_t* vt = (uint16_t*)ws;              ws += nqkv * 2;
    uint16_t* xh = (uint16_t*)ws;              ws += nx * 2;
    uint16_t* xl = (uint16_t*)ws;              ws += nx * 2;
    uint16_t* wh = (uint16_t*)ws;              ws += nw * 2;
    uint16_t* wl = (uint16_t*)ws;              ws += nw * 2;

    // converts (Q pre-scaled by 0.125*log2e; merged Q/K launch)
    k_splitqk<<<dim3((int)(nqkv / 4 / 256), 2), 256, 0, stream>>>(
        q, k, qh, ql, kh, kl, (int)(nqkv / 4));
    k_split<<<(int)(nw / 4 / 256), 256, 0, stream>>>(pw, wh, wl, (int)(nw / 4));
    k_vt<<<dim3(NCTX / 64, BATCH * HEADS), 256, 0, stream>>>(v, vt);

    // attention
    k_attn<<<dim3(NCTX / 64, BATCH * HEADS), 256, 0, stream>>>(qh, ql, kh, kl, vt, xh, xl);

    // projection
    k_proj<<<dim3((BATCH * NCTX) / 64, EMB / 64), 256, 0, stream>>>(xh, xl, wh, wl, pb, out);
}

// Round 5
// 117.831 us; speedup vs baseline: 2.0363x; 1.0464x over previous
//
#include <hip/hip_runtime.h>
#include <cstdint>

typedef short bf16x8 __attribute__((ext_vector_type(8)));
typedef float f32x4 __attribute__((ext_vector_type(4)));
typedef uint16_t u16x4 __attribute__((ext_vector_type(4)));

#define MFMA_16x16x32(a, b, c) __builtin_amdgcn_mfma_f32_16x16x32_bf16((a), (b), (c), 0, 0, 0)

static constexpr int BATCH = 2;
static constexpr int HEADS = 12;
static constexpr int NCTX  = 2048;
static constexpr int DH    = 64;
static constexpr int EMB   = 768;

// 0.125 * log2(e): Q pre-scale so softmax runs in exp2 domain
static constexpr float QSCALE = 0.125f * 1.44269504088896340736f;

// ---------- bf16 helpers (raw-bit, RN rounding) ----------
__device__ __forceinline__ uint16_t f2bf(float x) {
    uint32_t u = __float_as_uint(x);
    u += 0x7FFFu + ((u >> 16) & 1u);
    return (uint16_t)(u >> 16);
}
__device__ __forceinline__ float bf2f(uint16_t h) {
    return __uint_as_float(((uint32_t)h) << 16);
}
__device__ __forceinline__ uint32_t cvt_pk_bf16(float lo, float hi) {
    uint32_t r;
    asm("v_cvt_pk_bf16_f32 %0, %1, %2" : "=v"(r) : "v"(lo), "v"(hi));
    return r;
}

// ---------- merged Q/K split convert (blockIdx.y: 0=Q pre-scaled, 1=K) ----------
__global__ void k_splitqk(const float* __restrict__ q, const float* __restrict__ k,
                          uint16_t* __restrict__ qh, uint16_t* __restrict__ ql,
                          uint16_t* __restrict__ kh, uint16_t* __restrict__ kl, int n4) {
    int i = blockIdx.x * blockDim.x + threadIdx.x;
    if (i >= n4) return;
    const bool isK = blockIdx.y != 0;
    const float* src = isK ? k : q;
    uint16_t* hi = isK ? kh : qh;
    uint16_t* lo = isK ? kl : ql;
    const float scale = isK ? 1.0f : QSCALE;
    float4 v = reinterpret_cast<const float4*>(src)[i];
    v.x *= scale; v.y *= scale; v.z *= scale; v.w *= scale;
    uint16_t h0 = f2bf(v.x), h1 = f2bf(v.y), h2 = f2bf(v.z), h3 = f2bf(v.w);
    u16x4 hv = {h0, h1, h2, h3};
    u16x4 lv = {f2bf(v.x - bf2f(h0)), f2bf(v.y - bf2f(h1)),
                f2bf(v.z - bf2f(h2)), f2bf(v.w - bf2f(h3))};
    reinterpret_cast<u16x4*>(hi)[i] = hv;
    reinterpret_cast<u16x4*>(lo)[i] = lv;
}

// ---------- plain split (for W) ----------
__global__ void k_split(const float* __restrict__ src, uint16_t* __restrict__ hi,
                        uint16_t* __restrict__ lo, int n4) {
    int i = blockIdx.x * blockDim.x + threadIdx.x;
    if (i >= n4) return;
    float4 v = reinterpret_cast<const float4*>(src)[i];
    uint16_t h0 = f2bf(v.x), h1 = f2bf(v.y), h2 = f2bf(v.z), h3 = f2bf(v.w);
    u16x4 hv = {h0, h1, h2, h3};
    u16x4 lv = {f2bf(v.x - bf2f(h0)), f2bf(v.y - bf2f(h1)),
                f2bf(v.z - bf2f(h2)), f2bf(v.w - bf2f(h3))};
    reinterpret_cast<u16x4*>(hi)[i] = hv;
    reinterpret_cast<u16x4*>(lo)[i] = lv;
}

// ---------- V transpose+convert: [bh][n][64] fp32 -> [bh][64][n] bf16 ----------
__global__ __launch_bounds__(256) void k_vt(const float* __restrict__ v,
                                            uint16_t* __restrict__ vt) {
    const int bh = blockIdx.y;
    const int n0 = blockIdx.x * 64;
    const int t  = threadIdx.x;
    __shared__ uint16_t tileT[64][72];   // [d][n_local]

    const int r  = t >> 2;          // n-row within tile (0..63)
    const int cc = (t & 3) * 16;    // d-col base
    const float* vp = v + ((size_t)bh * NCTX + n0 + r) * DH + cc;
#pragma unroll
    for (int u = 0; u < 4; ++u) {
        float4 x = reinterpret_cast<const float4*>(vp)[u];
        tileT[cc + 4 * u + 0][r] = f2bf(x.x);
        tileT[cc + 4 * u + 1][r] = f2bf(x.y);
        tileT[cc + 4 * u + 2][r] = f2bf(x.z);
        tileT[cc + 4 * u + 3][r] = f2bf(x.w);
    }
    __syncthreads();
    const int d  = t >> 2;          // d-row (0..63)
    const int nc = (t & 3) * 16;    // n chunk
    uint16_t* op = vt + ((size_t)bh * DH + d) * NCTX + n0 + nc;
#pragma unroll
    for (int u = 0; u < 2; ++u) {
        bf16x8 x = *reinterpret_cast<const bf16x8*>(&tileT[d][nc + 8 * u]);
        *reinterpret_cast<bf16x8*>(op + 8 * u) = x;
    }
}

// ---------- flash attention (round-3 proven version, byte-identical) ----------
// grid: (NCTX/64, BATCH*HEADS), block: 256 (4 waves). Wave owns 16 q-rows.
// Swapped QK^T (S^T in regs: lane holds q=c, kv=16nf+4g+r) -> cheap softmax,
// vectorized P writes, exp2 domain, deferred max, reg-prefetch double buffer.
__global__ __launch_bounds__(256) void k_attn(
        const uint16_t* __restrict__ qh, const uint16_t* __restrict__ ql,
        const uint16_t* __restrict__ kh, const uint16_t* __restrict__ kl,
        const uint16_t* __restrict__ vt,
        uint16_t* __restrict__ xh, uint16_t* __restrict__ xl) {
    const int bh = blockIdx.y;
    const int b  = bh / HEADS;
    const int h  = bh % HEADS;
    const int tid = threadIdx.x;
    const int w = tid >> 6;
    const int l = tid & 63;
    const int g = l >> 4;    // 16-lane group 0..3
    const int c = l & 15;

    __shared__ uint16_t Kh_s[64][72];
    __shared__ uint16_t Kl_s[64][72];
    __shared__ uint16_t Vt_s[64][72];   // [d][kv]
    __shared__ uint16_t P_s [4][16][72];  // [wave][q][kv]

    const int q0 = blockIdx.x * 64 + w * 16;

    // Q fragments (pre-scaled by 0.125*log2e at split time)
    const size_t qoff = ((size_t)bh * NCTX + q0 + c) * DH + 8 * g;
    bf16x8 qa_h[2], qa_l[2];
    qa_h[0] = *reinterpret_cast<const bf16x8*>(qh + qoff);
    qa_h[1] = *reinterpret_cast<const bf16x8*>(qh + qoff + 32);
    qa_l[0] = *reinterpret_cast<const bf16x8*>(ql + qoff);
    qa_l[1] = *reinterpret_cast<const bf16x8*>(ql + qoff + 32);

    f32x4 zero = {0.f, 0.f, 0.f, 0.f};
    f32x4 o[4] = {zero, zero, zero, zero};
    float m = -1e30f;     // running max (log2 units), per q=c (uniform across groups)
    float lsum = 0.f;     // lane-partial softmax denominator for q=c

    // staging decomposition: 256 thr -> 32 rows x 8 chunks, two row-passes
    const int srow = tid >> 3;      // 0..31
    const int sch  = tid & 7;       // 0..7

    const uint16_t* kh_b = kh + (size_t)bh * NCTX * DH + srow * DH + sch * 8;
    const uint16_t* kl_b = kl + (size_t)bh * NCTX * DH + srow * DH + sch * 8;
    const uint16_t* vt_b = vt + (size_t)bh * DH * NCTX + srow * NCTX + sch * 8;

    // prologue: stage tile 0
    {
        bf16x8 a0 = *reinterpret_cast<const bf16x8*>(kh_b);
        bf16x8 a1 = *reinterpret_cast<const bf16x8*>(kh_b + 32 * DH);
        bf16x8 b0 = *reinterpret_cast<const bf16x8*>(kl_b);
        bf16x8 b1 = *reinterpret_cast<const bf16x8*>(kl_b + 32 * DH);
        bf16x8 v0 = *reinterpret_cast<const bf16x8*>(vt_b);
        bf16x8 v1 = *reinterpret_cast<const bf16x8*>(vt_b + 32 * NCTX);
        *reinterpret_cast<bf16x8*>(&Kh_s[srow][sch * 8])      = a0;
        *reinterpret_cast<bf16x8*>(&Kh_s[srow + 32][sch * 8]) = a1;
        *reinterpret_cast<bf16x8*>(&Kl_s[srow][sch * 8])      = b0;
        *reinterpret_cast<bf16x8*>(&Kl_s[srow + 32][sch * 8]) = b1;
        *reinterpret_cast<bf16x8*>(&Vt_s[srow][sch * 8])      = v0;
        *reinterpret_cast<bf16x8*>(&Vt_s[srow + 32][sch * 8]) = v1;
    }
    __syncthreads();

    for (int t = 0; t < NCTX / 64; ++t) {
        // issue next-tile loads early (hide latency under compute)
        bf16x8 nkh0, nkh1, nkl0, nkl1, nv0, nv1;
        const bool pf = (t + 1) < NCTX / 64;
        if (pf) {
            const size_t ko = (size_t)(t + 1) * 64 * DH;
            const size_t vo = (size_t)(t + 1) * 64;
            nkh0 = *reinterpret_cast<const bf16x8*>(kh_b + ko);
            nkh1 = *reinterpret_cast<const bf16x8*>(kh_b + ko + 32 * DH);
            nkl0 = *reinterpret_cast<const bf16x8*>(kl_b + ko);
            nkl1 = *reinterpret_cast<const bf16x8*>(kl_b + ko + 32 * DH);
            nv0  = *reinterpret_cast<const bf16x8*>(vt_b + vo);
            nv1  = *reinterpret_cast<const bf16x8*>(vt_b + vo + 32 * NCTX);
        }

        // ---- S^T = (K Q^T) (3-term split). s[nf][r] = S[kv=16nf+4g+r][q=c]
        f32x4 s[4] = {zero, zero, zero, zero};
        __builtin_amdgcn_s_setprio(1);
#pragma unroll
        for (int nf = 0; nf < 4; ++nf) {
#pragma unroll
            for (int kf = 0; kf < 2; ++kf) {
                bf16x8 bhf = *reinterpret_cast<const bf16x8*>(&Kh_s[nf * 16 + c][kf * 32 + 8 * g]);
                bf16x8 blf = *reinterpret_cast<const bf16x8*>(&Kl_s[nf * 16 + c][kf * 32 + 8 * g]);
                s[nf] = MFMA_16x16x32(bhf, qa_h[kf], s[nf]);
                s[nf] = MFMA_16x16x32(blf, qa_h[kf], s[nf]);
                s[nf] = MFMA_16x16x32(bhf, qa_l[kf], s[nf]);
            }
        }
        __builtin_amdgcn_s_setprio(0);

        // ---- softmax (log2 domain). Row (per-q) reduce: in-lane + 2 shfls.
        float smax = s[0][0];
#pragma unroll
        for (int nf = 0; nf < 4; ++nf)
#pragma unroll
            for (int r = 0; r < 4; ++r) smax = fmaxf(smax, s[nf][r]);
        smax = fmaxf(smax, __shfl_xor(smax, 16));
        smax = fmaxf(smax, __shfl_xor(smax, 32));

        // deferred max (THR = 11 in log2 units ~= e^8)
        if (!__all(smax <= m + 11.0f)) {
            float mnew = fmaxf(m, smax);
            float corr = __builtin_amdgcn_exp2f(m - mnew);
            m = mnew;
            lsum *= corr;
#pragma unroll
            for (int r = 0; r < 4; ++r) {
                float cr = __shfl(corr, 4 * g + r);   // corr for q-local 4g+r
#pragma unroll
                for (int f = 0; f < 4; ++f) o[f][r] *= cr;
            }
        }

        // p = exp2(s - m); pack pairs and write 4 contiguous kv per lane (b64)
#pragma unroll
        for (int nf = 0; nf < 4; ++nf) {
            float p0 = __builtin_amdgcn_exp2f(s[nf][0] - m);
            float p1 = __builtin_amdgcn_exp2f(s[nf][1] - m);
            float p2 = __builtin_amdgcn_exp2f(s[nf][2] - m);
            float p3 = __builtin_amdgcn_exp2f(s[nf][3] - m);
            lsum += (p0 + p1) + (p2 + p3);
            uint2 pk;
            pk.x = cvt_pk_bf16(p0, p1);
            pk.y = cvt_pk_bf16(p2, p3);
            *reinterpret_cast<uint2*>(&P_s[w][c][16 * nf + 4 * g]) = pk;
        }

        // ---- O += P V (Vt_s gives contiguous B-fragments)
        bf16x8 pa0 = *reinterpret_cast<const bf16x8*>(&P_s[w][c][8 * g]);
        bf16x8 pa1 = *reinterpret_cast<const bf16x8*>(&P_s[w][c][32 + 8 * g]);
        __builtin_amdgcn_s_setprio(1);
#pragma unroll
        for (int f = 0; f < 4; ++f) {
            bf16x8 b0 = *reinterpret_cast<const bf16x8*>(&Vt_s[f * 16 + c][8 * g]);
            bf16x8 b1 = *reinterpret_cast<const bf16x8*>(&Vt_s[f * 16 + c][32 + 8 * g]);
            o[f] = MFMA_16x16x32(pa0, b0, o[f]);
            o[f] = MFMA_16x16x32(pa1, b1, o[f]);
        }
        __builtin_amdgcn_s_setprio(0);

        __syncthreads();   // all waves done reading this tile
        if (pf) {
            *reinterpret_cast<bf16x8*>(&Kh_s[srow][sch * 8])      = nkh0;
            *reinterpret_cast<bf16x8*>(&Kh_s[srow + 32][sch * 8]) = nkh1;
            *reinterpret_cast<bf16x8*>(&Kl_s[srow][sch * 8])      = nkl0;
            *reinterpret_cast<bf16x8*>(&Kl_s[srow + 32][sch * 8]) = nkl1;
            *reinterpret_cast<bf16x8*>(&Vt_s[srow][sch * 8])      = nv0;
            *reinterpret_cast<bf16x8*>(&Vt_s[srow + 32][sch * 8]) = nv1;
        }
        __syncthreads();   // next tile visible
    }

    // ---- epilogue: reduce l over the 4 groups, normalize, split, store
    lsum += __shfl_xor(lsum, 16);
    lsum += __shfl_xor(lsum, 32);
    const float linv = 1.0f / lsum;

    const size_t xbase = ((size_t)b * NCTX + q0) * EMB + h * DH;
#pragma unroll
    for (int r = 0; r < 4; ++r) {
        float lr = __shfl(linv, 4 * g + r);   // 1/l for q-local 4g+r
#pragma unroll
        for (int f = 0; f < 4; ++f) {
            float v = o[f][r] * lr;
            uint16_t hv = f2bf(v);
            uint16_t lv2 = f2bf(v - bf2f(hv));
            size_t addr = xbase + (size_t)(4 * g + r) * EMB + f * 16 + c;
            xh[addr] = hv;
            xl[addr] = lv2;
        }
    }
}

// ---------- projection GEMM: Y[4096x768] = X @ W^T + bias (3-term split) ----------
// R3 barrier skeleton + clamped-index register prefetch (no conditionals, no
// uninitialized values): next k-step W/X loads issue before the MFMA cluster.
__global__ __launch_bounds__(256) void k_proj(
        const uint16_t* __restrict__ xh, const uint16_t* __restrict__ xl,
        const uint16_t* __restrict__ wh, const uint16_t* __restrict__ wl,
        const float* __restrict__ bias, float* __restrict__ out) {
    const int tid = threadIdx.x;
    const int w = tid >> 6;
    const int l = tid & 63;
    const int g = l >> 4;
    const int c = l & 15;
    const int m0 = blockIdx.x * 64 + w * 16;
    const int n0 = blockIdx.y * 64;

    __shared__ uint16_t Wh_s[64][40];
    __shared__ uint16_t Wl_s[64][40];

    f32x4 zero = {0.f, 0.f, 0.f, 0.f};
    f32x4 acc[4] = {zero, zero, zero, zero};

    const int srow = tid >> 2;   // 0..63
    const int sch  = tid & 3;    // 0..3
    constexpr int KSTEPS = EMB / 32;   // 24

    const uint16_t* whp = wh + (size_t)(n0 + srow) * EMB + sch * 8;
    const uint16_t* wlp = wl + (size_t)(n0 + srow) * EMB + sch * 8;
    const uint16_t* xhp = xh + (size_t)(m0 + c) * EMB + 8 * g;
    const uint16_t* xlp = xl + (size_t)(m0 + c) * EMB + 8 * g;

    // prologue loads (k-step 0)
    bf16x8 wldh = *reinterpret_cast<const bf16x8*>(whp);
    bf16x8 wldl = *reinterpret_cast<const bf16x8*>(wlp);
    bf16x8 ah   = *reinterpret_cast<const bf16x8*>(xhp);
    bf16x8 al   = *reinterpret_cast<const bf16x8*>(xlp);

    for (int ks = 0; ks < KSTEPS; ++ks) {
        __syncthreads();     // previous iteration's readers are done (no-op at ks=0)
        *reinterpret_cast<bf16x8*>(&Wh_s[srow][sch * 8]) = wldh;
        *reinterpret_cast<bf16x8*>(&Wl_s[srow][sch * 8]) = wldl;
        __syncthreads();     // stores visible to all waves

        // prefetch next k-step (clamped on the last iteration: re-reads k-step
        // KSTEPS-1; values are dead after the final loop trip — always in-bounds)
        const int ksn = (ks + 1 < KSTEPS) ? (ks + 1) : (KSTEPS - 1);
        bf16x8 wldh_n = *reinterpret_cast<const bf16x8*>(whp + (size_t)ksn * 32);
        bf16x8 wldl_n = *reinterpret_cast<const bf16x8*>(wlp + (size_t)ksn * 32);
        bf16x8 ah_n   = *reinterpret_cast<const bf16x8*>(xhp + (size_t)ksn * 32);
        bf16x8 al_n   = *reinterpret_cast<const bf16x8*>(xlp + (size_t)ksn * 32);

        __builtin_amdgcn_s_setprio(1);
#pragma unroll
        for (int nf = 0; nf < 4; ++nf) {
            bf16x8 bhf = *reinterpret_cast<const bf16x8*>(&Wh_s[nf * 16 + c][8 * g]);
            bf16x8 blf = *reinterpret_cast<const bf16x8*>(&Wl_s[nf * 16 + c][8 * g]);
            acc[nf] = MFMA_16x16x32(ah, bhf, acc[nf]);
            acc[nf] = MFMA_16x16x32(al, bhf, acc[nf]);
            acc[nf] = MFMA_16x16x32(ah, blf, acc[nf]);
        }
        __builtin_amdgcn_s_setprio(0);

        wldh = wldh_n; wldl = wldl_n; ah = ah_n; al = al_n;
    }

#pragma unroll
    for (int nf = 0; nf < 4; ++nf) {
#pragma unroll
        for (int r = 0; r < 4; ++r) {
            int row = m0 + g * 4 + r;
            int col = n0 + nf * 16 + c;
            out[(size_t)row * EMB + col] = acc[nf][r] + bias[col];
        }
    }
}

extern "C" void kernel_launch(void* const* d_in, const int* in_sizes, int n_in,
                              void* d_out, int out_size, void* d_ws, size_t ws_size,
                              hipStream_t stream) {
    const float* q    = (const float*)d_in[0];
    const float* k    = (const float*)d_in[1];
    const float* v    = (const float*)d_in[2];
    const float* pw   = (const float*)d_in[3];
    const float* pb   = (const float*)d_in[4];
    float* out = (float*)d_out;

    const size_t nqkv = (size_t)BATCH * HEADS * NCTX * DH;   // 3,145,728
    const size_t nx   = (size_t)BATCH * NCTX * EMB;          // 3,145,728
    const size_t nw   = (size_t)EMB * EMB;                   //   589,824

    uint8_t* ws = (uint8_t*)d_ws;
    uint16_t* qh = (uint16_t*)ws;              ws += nqkv * 2;
    uint16_t* ql = (uint16_t*)ws;              ws += nqkv * 2;
    uint16_t* kh = (uint16_t*)ws;              ws += nqkv * 2;
    uint16_t* kl = (uint16_t*)ws;              ws += nqkv * 2;
    uint16_t* vt = (uint16_t*)ws;              ws += nqkv * 2;
    uint16_t* xh = (uint16_t*)ws;              ws += nx * 2;
    uint16_t* xl = (uint16_t*)ws;              ws += nx * 2;
    uint16_t* wh = (uint16_t*)ws;              ws += nw * 2;
    uint16_t* wl = (uint16_t*)ws;              ws += nw * 2;

    // converts (Q pre-scaled by 0.125*log2e; merged Q/K launch)
    k_splitqk<<<dim3((int)(nqkv / 4 / 256), 2), 256, 0, stream>>>(
        q, k, qh, ql, kh, kl, (int)(nqkv / 4));
    k_split<<<(int)(nw / 4 / 256), 256, 0, stream>>>(pw, wh, wl, (int)(nw / 4));
    k_vt<<<dim3(NCTX / 64, BATCH * HEADS), 256, 0, stream>>>(v, vt);

    // attention (round-3 proven 4-wave version)
    k_attn<<<dim3(NCTX / 64, BATCH * HEADS), 256, 0, stream>>>(qh, ql, kh, kl, vt, xh, xl);

    // projection
    k_proj<<<dim3((BATCH * NCTX) / 64, EMB / 64), 256, 0, stream>>>(xh, xl, wh, wl, pb, out);
}